// Round 4
// baseline (1288.874 us; speedup 1.0000x reference)
//
#include <hip/hip_runtime.h>

typedef unsigned short UST;
typedef __bf16 bf16x8 __attribute__((ext_vector_type(8)));
typedef float f32x4 __attribute__((ext_vector_type(4)));
typedef float f32x8 __attribute__((ext_vector_type(8)));

__device__ __forceinline__ UST f2bf(float f) {
  return __builtin_bit_cast(UST, (__bf16)f);
}

// split 8 fp32 -> bf16 hi + bf16 lo (residual), packed 16B each
__device__ __forceinline__ void split8v(f32x8 f, uint4& h, uint4& l) {
  UST hh[8], ll[8];
#pragma unroll
  for (int i = 0; i < 8; ++i) {
    float v = f[i];
    __bf16 hb = (__bf16)v;
    hh[i] = __builtin_bit_cast(UST, hb);
    ll[i] = __builtin_bit_cast(UST, (__bf16)(v - (float)hb));
  }
  h = *(uint4*)hh; l = *(uint4*)ll;
}

// chunk-local row p = bn_local*64 + t  ->  absolute token row b*12544 + t*196 + n
__device__ __forceinline__ size_t tok_row(int p, int bn0) {
  const int bn = bn0 + (p >> 6);
  const int b  = bn / 196;
  const int n  = bn - b * 196;
  return (size_t)b * 12544 + (size_t)(p & 63) * 196 + (size_t)n;
}

// C = A @ Bt^T (+bias), all fp32 I/O; internally split-bf16 (3 MFMA).
// A: MxK, Bt: NxK, C: MxN. M%128==0, N%128==0, K%32==0.
// pmode: 0 plain, 1 A-rows via tok_row, 2 C-rows via tok_row.
__global__ __launch_bounds__(256) void gemm_bt_split(
    const float* __restrict__ A, const float* __restrict__ Bt,
    const float* __restrict__ bias, float* __restrict__ C,
    int M, int N, int K, int pmode, int bn0)
{
  __shared__ __align__(16) UST Ah[128 * 32];
  __shared__ __align__(16) UST Al[128 * 32];
  __shared__ __align__(16) UST Bh[128 * 32];
  __shared__ __align__(16) UST Bl[128 * 32];

  const int tid  = threadIdx.x;
  const int lane = tid & 63;
  const int wv   = tid >> 6;
  const int wr   = wv >> 1;
  const int wc   = wv & 1;
  const int lm   = lane & 15;
  const int lq   = lane >> 4;

  const int m0 = blockIdx.y * 128;
  const int n0 = blockIdx.x * 128;

  f32x4 acc[4][4] = {};

  // staging: thread covers (row sr, cols sc..sc+7) and (row sr+64, same cols)
  const int sr = tid >> 2;               // 0..63
  const int sc = (tid & 3) * 8;          // 0,8,16,24
  const int e1 = sr * 32 + sc;
  const int e2 = (sr + 64) * 32 + sc;

  const int ar1 = m0 + sr, ar2 = ar1 + 64;
  const size_t ga1 = (pmode == 1) ? tok_row(ar1, bn0) : (size_t)ar1;
  const size_t ga2 = (pmode == 1) ? tok_row(ar2, bn0) : (size_t)ar2;
  const float* Arow1 = A + ga1 * K + sc;
  const float* Arow2 = A + ga2 * K + sc;
  const float* Brow1 = Bt + (size_t)(n0 + sr) * K + sc;
  const float* Brow2 = Bt + (size_t)(n0 + sr + 64) * K + sc;

  for (int k0 = 0; k0 < K; k0 += 32) {
    f32x8 a1 = *(const f32x8*)(Arow1 + k0);
    f32x8 b1 = *(const f32x8*)(Brow1 + k0);
    f32x8 a2 = *(const f32x8*)(Arow2 + k0);
    f32x8 b2 = *(const f32x8*)(Brow2 + k0);
    uint4 a1h, a1l, b1h, b1l, a2h, a2l, b2h, b2l;
    split8v(a1, a1h, a1l);
    split8v(b1, b1h, b1l);
    split8v(a2, a2h, a2l);
    split8v(b2, b2h, b2l);
    __syncthreads();                     // prior iter's frag reads done
    *(uint4*)(Ah + e1) = a1h;  *(uint4*)(Al + e1) = a1l;
    *(uint4*)(Bh + e1) = b1h;  *(uint4*)(Bl + e1) = b1l;
    *(uint4*)(Ah + e2) = a2h;  *(uint4*)(Al + e2) = a2l;
    *(uint4*)(Bh + e2) = b2h;  *(uint4*)(Bl + e2) = b2l;
    __syncthreads();

    bf16x8 afh[4], afl[4], bfh[4], bfl[4];
#pragma unroll
    for (int i = 0; i < 4; ++i) {
      const int off = (wr * 64 + i * 16 + lm) * 32 + lq * 8;
      afh[i] = *(const bf16x8*)(Ah + off);
      afl[i] = *(const bf16x8*)(Al + off);
    }
#pragma unroll
    for (int j = 0; j < 4; ++j) {
      const int off = (wc * 64 + j * 16 + lm) * 32 + lq * 8;
      bfh[j] = *(const bf16x8*)(Bh + off);
      bfl[j] = *(const bf16x8*)(Bl + off);
    }
#pragma unroll
    for (int i = 0; i < 4; ++i)
#pragma unroll
      for (int j = 0; j < 4; ++j) {
        acc[i][j] = __builtin_amdgcn_mfma_f32_16x16x32_bf16(afh[i], bfh[j], acc[i][j], 0, 0, 0);
        acc[i][j] = __builtin_amdgcn_mfma_f32_16x16x32_bf16(afh[i], bfl[j], acc[i][j], 0, 0, 0);
        acc[i][j] = __builtin_amdgcn_mfma_f32_16x16x32_bf16(afl[i], bfh[j], acc[i][j], 0, 0, 0);
      }
  }

  // epilogue: C/D layout col=lane&15, row=quad*4+reg; fp32 stores
#pragma unroll
  for (int j = 0; j < 4; ++j) {
    const int n = n0 + wc * 64 + j * 16 + lm;
    const float bv = bias ? bias[n] : 0.0f;
#pragma unroll
    for (int i = 0; i < 4; ++i) {
      const int pb = m0 + wr * 64 + i * 16 + lq * 4;
#pragma unroll
      for (int r = 0; r < 4; ++r) {
        const int p = pb + r;
        const size_t g = (pmode == 2) ? tok_row(p, bn0) : (size_t)p;
        C[g * (size_t)N + n] = acc[i][j][r] + bv;
      }
    }
  }
}

// One block per (chunk-local bn, head): causal attention, T=64, hd=64.
// qkv: chunk-local (64*NBc, 2304) fp32.  out: chunk-local (64*NBc, 768) fp32.
#define SQ_STRIDE 67
#define TS 72

__global__ __launch_bounds__(256) void attn64(
    const float* __restrict__ qkv, float* __restrict__ outp)
{
  const int nl = blockIdx.x;
  const int h  = blockIdx.y;

  __shared__ __align__(16) UST Qs[64 * TS];
  __shared__ __align__(16) UST Ks[64 * TS];
  __shared__ __align__(16) UST Vt[64 * TS];   // V^T, XOR-swizzled k-blocks
  __shared__ __align__(16) UST Ps[64 * TS];   // exp(S-M) bf16
  __shared__ float Ss[64 * SQ_STRIDE];
  __shared__ float red[4 * 64];
  __shared__ float denom[64];

  const int tid  = threadIdx.x;
  const int lane = tid & 63;
  const int wv   = tid >> 6;
  const int lm   = lane & 15;
  const int lq   = lane >> 4;

  // ---- stage Q, K (bf16 hi) and V^T (bf16 hi, XOR-swizzled) ----
#pragma unroll
  for (int it = 0; it < 4; ++it) {
    const int idx = it * 256 + tid;      // float4-chunk id, 0..1023
    const int t   = idx >> 4;            // row 0..63
    const int f0  = (idx & 15) * 4;      // col 0..60
    const size_t row = (size_t)(nl * 64 + t) * 2304 + h * 64;
    float4 qv = *(const float4*)(qkv + row + f0);
    float4 kv = *(const float4*)(qkv + row + 768 + f0);
    float4 vv = *(const float4*)(qkv + row + 1536 + f0);
    UST q4[4] = {f2bf(qv.x), f2bf(qv.y), f2bf(qv.z), f2bf(qv.w)};
    UST k4[4] = {f2bf(kv.x), f2bf(kv.y), f2bf(kv.z), f2bf(kv.w)};
    *(uint2*)(&Qs[t * TS + f0]) = *(uint2*)q4;
    *(uint2*)(&Ks[t * TS + f0]) = *(uint2*)k4;
    const float vf[4] = {vv.x, vv.y, vv.z, vv.w};
    const int cb = t >> 3;
#pragma unroll
    for (int i = 0; i < 4; ++i) {
      const int d = f0 + i;
      // element V[t][d] stored at Vt[d][ ((cb ^ (d>>3))&7)*8 + (t&7) ]
      Vt[d * TS + (((cb ^ (d >> 3)) & 7) << 3) + (t & 7)] = f2bf(vf[i]);
    }
  }
  __syncthreads();

  // ---- S = Q K^T : wave wv computes rows [wv*16, wv*16+16) x all 64 cols ----
  f32x4 accS[4] = {};
#pragma unroll
  for (int s = 0; s < 2; ++s) {
    bf16x8 aq = *(const bf16x8*)(&Qs[(wv * 16 + lm) * TS + s * 32 + lq * 8]);
#pragma unroll
    for (int j = 0; j < 4; ++j) {
      bf16x8 bk = *(const bf16x8*)(&Ks[(j * 16 + lm) * TS + s * 32 + lq * 8]);
      accS[j] = __builtin_amdgcn_mfma_f32_16x16x32_bf16(aq, bk, accS[j], 0, 0, 0);
    }
  }

  // write masked, scaled scores (C/D layout: col=lane&15, row=quad*4+reg)
#pragma unroll
  for (int j = 0; j < 4; ++j)
#pragma unroll
    for (int r = 0; r < 4; ++r) {
      const int q = wv * 16 + lq * 4 + r;
      const int c = j * 16 + lm;
      Ss[q * SQ_STRIDE + c] = (c > q) ? -1e30f : accS[j][r] * 0.125f;
    }
  __syncthreads();

  // ---- softmax: thread handles row r=tid>>2, cols [seg*16, seg*16+16) ----
  {
    const int r = tid >> 2;
    const int seg = tid & 3;
    const float* srow = &Ss[r * SQ_STRIDE + seg * 16];
    float mx = -1e30f;
#pragma unroll
    for (int c = 0; c < 16; ++c) mx = fmaxf(mx, srow[c]);
    red[seg * 64 + r] = mx;
  }
  __syncthreads();
  {
    const int r = tid >> 2;
    const int seg = tid & 3;
    const float M = fmaxf(fmaxf(red[r], red[64 + r]), fmaxf(red[128 + r], red[192 + r]));
    float ssum = 0.f;
#pragma unroll
    for (int c = 0; c < 16; ++c) {
      const int col = seg * 16 + c;
      float e = 0.f;
      if (col <= r) e = __expf(Ss[r * SQ_STRIDE + col] - M);
      Ps[r * TS + col] = f2bf(e);
      ssum += e;
    }
    __syncthreads();           // all reads of red done before overwrite
    red[seg * 64 + r] = ssum;
  }
  __syncthreads();
  if (tid < 64)
    denom[tid] = red[tid] + red[64 + tid] + red[128 + tid] + red[192 + tid];
  __syncthreads();

  // ---- O = P V : wave wv computes rows [wv*16,+16) x d=0..63 ----
  f32x4 accO[4] = {};
#pragma unroll
  for (int s = 0; s < 2; ++s) {
    bf16x8 ap = *(const bf16x8*)(&Ps[(wv * 16 + lm) * TS + s * 32 + lq * 8]);
#pragma unroll
    for (int j = 0; j < 4; ++j) {
      const int d = j * 16 + lm;
      const int cb = s * 4 + lq;
      bf16x8 bv = *(const bf16x8*)(&Vt[d * TS + (((cb ^ (d >> 3)) & 7) << 3)]);
      accO[j] = __builtin_amdgcn_mfma_f32_16x16x32_bf16(ap, bv, accO[j], 0, 0, 0);
    }
  }

  float inv[4];
#pragma unroll
  for (int r = 0; r < 4; ++r) inv[r] = 1.0f / denom[wv * 16 + lq * 4 + r];
#pragma unroll
  for (int j = 0; j < 4; ++j)
#pragma unroll
    for (int r = 0; r < 4; ++r) {
      const int q = wv * 16 + lq * 4 + r;
      const int d = j * 16 + lm;
      outp[(size_t)(nl * 64 + q) * 768 + h * 64 + d] = accO[j][r] * inv[r];
    }
}

// Diagnostic fallback: ws too small -> fill output with 1.0f.
__global__ void fill_one(float* p, int n) {
  for (int i = blockIdx.x * 256 + threadIdx.x; i < n; i += gridDim.x * 256)
    p[i] = 1.0f;
}

extern "C" void kernel_launch(void* const* d_in, const int* in_sizes, int n_in,
                              void* d_out, int out_size, void* d_ws, size_t ws_size,
                              hipStream_t stream)
{
  const float* x      = (const float*)d_in[0];
  const float* w_qkv  = (const float*)d_in[1];
  const float* w_proj = (const float*)d_in[2];
  const float* b_proj = (const float*)d_in[3];
  float* out = (float*)d_out;

  // 784 (b,n) pairs; chunk needs NBc * 64 * (2304+768) * 4 B of ws.
  static const int cands[] = {784, 392, 196, 112, 56, 28, 14, 8, 4, 2};
  int NBc = 0;
  for (int i = 0; i < 10; ++i) {
    if ((size_t)cands[i] * 786432ull <= ws_size) { NBc = cands[i]; break; }
  }

  if (NBc == 0) {
    fill_one<<<512, 256, 0, stream>>>(out, out_size);
    return;
  }

  float* qkv_ws  = (float*)d_ws;
  float* attn_ws = qkv_ws + (size_t)NBc * 64 * 2304;

  const int Mi = NBc * 64;
  for (int bn0 = 0; bn0 < 784; bn0 += NBc) {
    dim3 g1(2304 / 128, Mi / 128);
    gemm_bt_split<<<g1, 256, 0, stream>>>(x, w_qkv, nullptr, qkv_ws,
                                          Mi, 2304, 768, /*pmode=*/1, bn0);
    dim3 ga(NBc, 12);
    attn64<<<ga, 256, 0, stream>>>(qkv_ws, attn_ws);
    dim3 g2(768 / 128, Mi / 128);
    gemm_bt_split<<<g2, 256, 0, stream>>>(attn_ws, w_proj, b_proj, out,
                                          Mi, 768, 768, /*pmode=*/2, bn0);
  }
}